// Round 21
// baseline (80.582 us; speedup 1.0000x reference)
//
#include <hip/hip_runtime.h>

#define EPS 1e-7f
#define NCH 29
#define SPB 128          // samples per block: 64 lanes x 2 packed (group0, group1)
#define ROWA 17          // padded float4 stride per sample in chunk staging buffer

// 256-thread / 4-wave blocks, 4 independent blocks per CU. Rationale (R20
// post-mortem): lockstep 8-wave blocks synchronize their flush bursts CU-wide,
// so the write path idles during compute phases. Four small desynced blocks
// drift out of phase -> store stream continuous at CU level while other
// blocks' VALU work proceeds. Keeps all proven fixes: lgkm-only barriers,
// tau hoisted before first store (vmem-free chunk loop), packed f32x2 math,
// SGPR weights, fire-and-forget chunked flush.

typedef float f32x2 __attribute__((ext_vector_type(2)));
typedef float nf4   __attribute__((ext_vector_type(4)));

__device__ __forceinline__ f32x2 splat2(float v) { f32x2 r; r.x = v; r.y = v; return r; }
__device__ __forceinline__ f32x2 fma2(f32x2 a, f32x2 b, f32x2 c) {
    return __builtin_elementwise_fma(a, b, c);
}
__device__ __forceinline__ f32x2 max2(f32x2 a, f32x2 b) {
    return __builtin_elementwise_max(a, b);
}
__device__ __forceinline__ f32x2 expc2(f32x2 a) {
    f32x2 r; r.x = __expf(a.x); r.y = __expf(a.y); return r;
}
__device__ __forceinline__ f32x2 rcp2(f32x2 a) {
    f32x2 r; r.x = __builtin_amdgcn_rcpf(a.x); r.y = __builtin_amdgcn_rcpf(a.y); return r;
}
__device__ __forceinline__ nf4 mk4(float a, float b, float c, float d) {
    nf4 r; r.x = a; r.y = b; r.z = c; r.w = d; return r;
}

// Barrier ordering LDS traffic only (lgkmcnt), NOT global stores (vmcnt).
__device__ __forceinline__ void barrier_lds_only() {
    asm volatile("s_waitcnt lgkmcnt(0)\n\ts_barrier" ::: "memory");
}

// Packed 2-sample MLP: weights wave-uniform (SGPR), data f32x2.
__device__ __forceinline__ void mlp7p(const f32x2 x[7],
    const float* __restrict__ W0, const float* __restrict__ b0,
    const float* __restrict__ W1, const float* __restrict__ b1,
    const float* __restrict__ W2, const float* __restrict__ b2,
    const float* __restrict__ W3, const float* __restrict__ b3,
    f32x2 e[3])
{
    const f32x2 zero = splat2(0.0f);
    f32x2 h0[5];
#pragma unroll
    for (int h = 0; h < 5; ++h) {
        f32x2 a = splat2(b0[h]);
#pragma unroll
        for (int f = 0; f < 7; ++f) a = fma2(x[f], splat2(W0[f * 5 + h]), a);
        h0[h] = max2(a, zero);
    }
    f32x2 h1[4];
#pragma unroll
    for (int k = 0; k < 4; ++k) {
        f32x2 a = splat2(b1[k]);
#pragma unroll
        for (int h = 0; h < 5; ++h) a = fma2(h0[h], splat2(W1[h * 4 + k]), a);
        h1[k] = max2(a, zero);
    }
    f32x2 h2[4];
#pragma unroll
    for (int k = 0; k < 4; ++k) {
        f32x2 a = splat2(b2[k]);
#pragma unroll
        for (int h = 0; h < 4; ++h) a = fma2(h1[h], splat2(W2[h * 4 + k]), a);
        h2[k] = max2(a, zero);
    }
    f32x2 l[3];
#pragma unroll
    for (int k = 0; k < 3; ++k) {
        f32x2 a = splat2(b3[k]);
#pragma unroll
        for (int h = 0; h < 4; ++h) a = fma2(h2[h], splat2(W3[h * 3 + k]), a);
        l[k] = a;
    }
    f32x2 m = max2(l[0], max2(l[1], l[2]));
    f32x2 e0 = expc2(l[0] - m);
    f32x2 e1 = expc2(l[1] - m);
    f32x2 e2 = expc2(l[2] - m);
    f32x2 rs = rcp2(e0 + e1 + e2);
    e[0] = e0 * rs; e[1] = e1 * rs; e[2] = e2 * rs;
}

// 4 blocks/CU: LDS 4 x 34.8KB = 139KB; VGPR cap 128 (4 waves/EU).
__global__ __launch_bounds__(256, 4) void lps_kernel(
    const float* __restrict__ tau, const float* __restrict__ mu, const float* __restrict__ mu_bar,
    const float* __restrict__ lw, const float* __restrict__ h2o, const float* __restrict__ o3,
    const float* __restrict__ co2, const float* __restrict__ uu, const float* __restrict__ n2o,
    const float* __restrict__ ch4,
    const float* __restrict__ Wd0, const float* __restrict__ bd0,
    const float* __restrict__ Wf0, const float* __restrict__ bf0,
    const float* __restrict__ Wd1, const float* __restrict__ bd1,
    const float* __restrict__ Wf1, const float* __restrict__ bf1,
    const float* __restrict__ Wd2, const float* __restrict__ bd2,
    const float* __restrict__ Wf2, const float* __restrict__ bf2,
    const float* __restrict__ Wd3, const float* __restrict__ bd3,
    const float* __restrict__ Wf3, const float* __restrict__ bf3,
    float* __restrict__ out, int N)
{
    __shared__ __align__(16) nf4 obuf[SPB * ROWA];   // 34816 B

    const int tid  = threadIdx.x;
    const int lane = tid & 63;
    const int wid  = __builtin_amdgcn_readfirstlane(tid >> 6);   // 0..3

    const long long base = (long long)blockIdx.x * SPB;
    const int s0 = (int)base + lane;
    const int s1 = s0 + 64;
    const int i0 = (s0 < N) ? s0 : (N - 1);
    const int i1 = (s1 < N) ? s1 : (N - 1);

    f32x2 mu2, mub2;
    mu2.x  = mu[i0];      mu2.y  = mu[i1];
    mub2.x = mu_bar[i0];  mub2.y = mu_bar[i1];
    const f32x2 rmu2  = rcp2(mu2 + splat2(EPS));
    const f32x2 rmub2 = rcp2(mub2 + splat2(EPS));

    f32x2 cons2[7];
    cons2[0].x = lw[i0];  cons2[0].y = lw[i1];
    cons2[1].x = h2o[i0]; cons2[1].y = h2o[i1];
    cons2[2].x = o3[i0];  cons2[2].y = o3[i1];
    cons2[3].x = co2[i0]; cons2[3].y = co2[i1];
    cons2[4].x = uu[i0];  cons2[4].y = uu[i1];
    cons2[5].x = n2o[i0]; cons2[5].y = n2o[i1];
    cons2[6].x = ch4[i0]; cons2[6].y = ch4[i1];

    // Hoist ALL tau loads before any store is issued: the chunk loop stays
    // vmem-load-free, so no s_waitcnt vmcnt can block compute behind the
    // draining store queue (R19 finding). 2 channel-visits per wave per chunk.
    f32x2 tauv1[4], tauv2[4];
#pragma unroll
    for (int k = 0; k < 4; ++k) {
        const int c1 = k * 8 + wid;          // 0..27, always valid
        const int c2 = c1 + 4;               // 4..31, guard at 29
        const int cc2 = (c2 < NCH) ? c2 : 0;
        tauv1[k].x = tau[(size_t)i0 * NCH + c1];
        tauv1[k].y = tau[(size_t)i1 * NCH + c1];
        tauv2[k].x = tau[(size_t)i0 * NCH + cc2];
        tauv2[k].y = tau[(size_t)i1 * NCH + cc2];
    }

    int nsamp = N - (int)base;
    if (nsamp > SPB) nsamp = SPB;
    nf4* out4 = (nf4*)out;

    // 4 chunk-phases: compute 8 channels (2 per wave) -> lgkm barrier ->
    // issue stores (fire-and-forget) -> lgkm barrier.
#pragma unroll
    for (int k = 0; k < 4; ++k) {
#pragma unroll
        for (int v = 0; v < 2; ++v) {
            const int c = k * 8 + wid + v * 4;   // wave-uniform channel
            if (c < NCH) {
                const f32x2 tt = v ? tauv2[k] : tauv1[k];
                const f32x2 td2 = expc2(-(tt * rmu2));
                const f32x2 tf2 = expc2(-(tt * rmub2));

                f32x2 x2[7];
                f32x2 ed[3], ef[3];
#pragma unroll
                for (int f = 0; f < 7; ++f) x2[f] = cons2[f] * rmu2;
                mlp7p(x2, Wd0 + c * 35, bd0 + c * 5, Wd1 + c * 20, bd1 + c * 4,
                          Wd2 + c * 16, bd2 + c * 4, Wd3 + c * 12, bd3 + c * 3, ed);
#pragma unroll
                for (int f = 0; f < 7; ++f) x2[f] = cons2[f] * rmub2;
                mlp7p(x2, Wf0 + c * 35, bf0 + c * 5, Wf1 + c * 20, bf1 + c * 4,
                          Wf2 + c * 16, bf2 + c * 4, Wf3 + c * 12, bf3 + c * 3, ef);

                const int r = (c - k * 8) * 2;   // local slot 0..15
                obuf[lane * ROWA + r]            = mk4(td2.x, tf2.x, ed[0].x, ed[1].x);
                obuf[lane * ROWA + r + 1]        = mk4(ed[2].x, ef[0].x, ef[1].x, ef[2].x);
                obuf[(lane + 64) * ROWA + r]     = mk4(td2.y, tf2.y, ed[0].y, ed[1].y);
                obuf[(lane + 64) * ROWA + r + 1] = mk4(ed[2].y, ef[0].y, ef[1].y, ef[2].y);
            }
        }

        barrier_lds_only();

        // issue chunk-k stores (fire-and-forget; drain overlaps other blocks)
        if (nsamp > 0) {
            if (k < 3) {
                const int tot = nsamp * 16;
                for (int i = tid; i < tot; i += 256) {
                    const int s = i >> 4, rr = i & 15;
                    out4[(base + s) * 58 + k * 16 + rr] = obuf[s * ROWA + rr];
                }
            } else {
                const int tot = nsamp * 10;   // 5 channels -> 10 f4 per sample
                for (int i = tid; i < tot; i += 256) {
                    const int s = i / 10, rr = i - s * 10;
                    out4[(base + s) * 58 + 48 + rr] = obuf[s * ROWA + rr];
                }
            }
        }

        barrier_lds_only();   // flush reads done -> obuf reusable
    }
}

extern "C" void kernel_launch(void* const* d_in, const int* in_sizes, int n_in,
                              void* d_out, int out_size, void* d_ws, size_t ws_size,
                              hipStream_t stream) {
    const float* tau    = (const float*)d_in[0];
    const float* mu     = (const float*)d_in[1];
    const float* mu_bar = (const float*)d_in[2];
    const float* lw     = (const float*)d_in[3];
    const float* h2o    = (const float*)d_in[4];
    const float* o3     = (const float*)d_in[5];
    const float* co2    = (const float*)d_in[6];
    const float* uu     = (const float*)d_in[7];
    const float* n2o    = (const float*)d_in[8];
    const float* ch4    = (const float*)d_in[9];

    const float* Wd0 = (const float*)d_in[10];
    const float* bd0 = (const float*)d_in[11];
    const float* Wf0 = (const float*)d_in[12];
    const float* bf0 = (const float*)d_in[13];
    const float* Wd1 = (const float*)d_in[14];
    const float* bd1 = (const float*)d_in[15];
    const float* Wf1 = (const float*)d_in[16];
    const float* bf1 = (const float*)d_in[17];
    const float* Wd2 = (const float*)d_in[18];
    const float* bd2 = (const float*)d_in[19];
    const float* Wf2 = (const float*)d_in[20];
    const float* bf2 = (const float*)d_in[21];
    const float* Wd3 = (const float*)d_in[22];
    const float* bd3 = (const float*)d_in[23];
    const float* Wf3 = (const float*)d_in[24];
    const float* bf3 = (const float*)d_in[25];

    float* out = (float*)d_out;
    int N = in_sizes[1];  // mu has N elements

    int blocks = (N + SPB - 1) / SPB;
    lps_kernel<<<blocks, 256, 0, stream>>>(
        tau, mu, mu_bar, lw, h2o, o3, co2, uu, n2o, ch4,
        Wd0, bd0, Wf0, bf0, Wd1, bd1, Wf1, bf1,
        Wd2, bd2, Wf2, bf2, Wd3, bd3, Wf3, bf3,
        out, N);
}

// Round 22
// 79.702 us; speedup vs baseline: 1.0110x; 1.0110x over previous
//
#include <hip/hip_runtime.h>

#define EPS 1e-7f
#define NCH 29
#define SPB 128          // samples per block: 64 lanes x 2 packed (group0, group1)
#define ROWA 17          // padded float4 stride per sample in chunk staging buffer

// R19 structure + per-block chunk-phase rotation: block b processes chunks in
// order (b, b+1, b+2, b+3) mod 4, so at any instant ~1/4 of blocks are in a
// flush phase -> the store stream is continuous at chip level instead of all
// blocks bursting in lockstep (R21 finding: write-path duty cycle only ~65%).

typedef float f32x2 __attribute__((ext_vector_type(2)));
typedef float nf4   __attribute__((ext_vector_type(4)));

__device__ __forceinline__ f32x2 splat2(float v) { f32x2 r; r.x = v; r.y = v; return r; }
__device__ __forceinline__ f32x2 fma2(f32x2 a, f32x2 b, f32x2 c) {
    return __builtin_elementwise_fma(a, b, c);
}
__device__ __forceinline__ f32x2 max2(f32x2 a, f32x2 b) {
    return __builtin_elementwise_max(a, b);
}
__device__ __forceinline__ f32x2 expc2(f32x2 a) {
    f32x2 r; r.x = __expf(a.x); r.y = __expf(a.y); return r;
}
__device__ __forceinline__ f32x2 rcp2(f32x2 a) {
    f32x2 r; r.x = __builtin_amdgcn_rcpf(a.x); r.y = __builtin_amdgcn_rcpf(a.y); return r;
}
__device__ __forceinline__ nf4 mk4(float a, float b, float c, float d) {
    nf4 r; r.x = a; r.y = b; r.z = c; r.w = d; return r;
}

// Barrier ordering LDS traffic only (lgkmcnt), NOT global stores (vmcnt).
__device__ __forceinline__ void barrier_lds_only() {
    asm volatile("s_waitcnt lgkmcnt(0)\n\ts_barrier" ::: "memory");
}

// Packed 2-sample MLP: weights wave-uniform (SGPR), data f32x2.
__device__ __forceinline__ void mlp7p(const f32x2 x[7],
    const float* __restrict__ W0, const float* __restrict__ b0,
    const float* __restrict__ W1, const float* __restrict__ b1,
    const float* __restrict__ W2, const float* __restrict__ b2,
    const float* __restrict__ W3, const float* __restrict__ b3,
    f32x2 e[3])
{
    const f32x2 zero = splat2(0.0f);
    f32x2 h0[5];
#pragma unroll
    for (int h = 0; h < 5; ++h) {
        f32x2 a = splat2(b0[h]);
#pragma unroll
        for (int f = 0; f < 7; ++f) a = fma2(x[f], splat2(W0[f * 5 + h]), a);
        h0[h] = max2(a, zero);
    }
    f32x2 h1[4];
#pragma unroll
    for (int k = 0; k < 4; ++k) {
        f32x2 a = splat2(b1[k]);
#pragma unroll
        for (int h = 0; h < 5; ++h) a = fma2(h0[h], splat2(W1[h * 4 + k]), a);
        h1[k] = max2(a, zero);
    }
    f32x2 h2[4];
#pragma unroll
    for (int k = 0; k < 4; ++k) {
        f32x2 a = splat2(b2[k]);
#pragma unroll
        for (int h = 0; h < 4; ++h) a = fma2(h1[h], splat2(W2[h * 4 + k]), a);
        h2[k] = max2(a, zero);
    }
    f32x2 l[3];
#pragma unroll
    for (int k = 0; k < 3; ++k) {
        f32x2 a = splat2(b3[k]);
#pragma unroll
        for (int h = 0; h < 4; ++h) a = fma2(h2[h], splat2(W3[h * 3 + k]), a);
        l[k] = a;
    }
    f32x2 m = max2(l[0], max2(l[1], l[2]));
    f32x2 e0 = expc2(l[0] - m);
    f32x2 e1 = expc2(l[1] - m);
    f32x2 e2 = expc2(l[2] - m);
    f32x2 rs = rcp2(e0 + e1 + e2);
    e[0] = e0 * rs; e[1] = e1 * rs; e[2] = e2 * rs;
}

// cap 102 VGPR (5 waves/EU); 2 blocks/CU, 16 waves/CU.
__global__ __launch_bounds__(512, 5) void lps_kernel(
    const float* __restrict__ tau, const float* __restrict__ mu, const float* __restrict__ mu_bar,
    const float* __restrict__ lw, const float* __restrict__ h2o, const float* __restrict__ o3,
    const float* __restrict__ co2, const float* __restrict__ uu, const float* __restrict__ n2o,
    const float* __restrict__ ch4,
    const float* __restrict__ Wd0, const float* __restrict__ bd0,
    const float* __restrict__ Wf0, const float* __restrict__ bf0,
    const float* __restrict__ Wd1, const float* __restrict__ bd1,
    const float* __restrict__ Wf1, const float* __restrict__ bf1,
    const float* __restrict__ Wd2, const float* __restrict__ bd2,
    const float* __restrict__ Wf2, const float* __restrict__ bf2,
    const float* __restrict__ Wd3, const float* __restrict__ bd3,
    const float* __restrict__ Wf3, const float* __restrict__ bf3,
    float* __restrict__ out, int N)
{
    __shared__ __align__(16) nf4 obuf[SPB * ROWA];   // 34816 B

    const int tid  = threadIdx.x;
    const int lane = tid & 63;
    const int wid  = __builtin_amdgcn_readfirstlane(tid >> 6);   // 0..7
    const int phase = blockIdx.x & 3;                // per-block chunk rotation

    const long long base = (long long)blockIdx.x * SPB;
    const int s0 = (int)base + lane;
    const int s1 = s0 + 64;
    const int i0 = (s0 < N) ? s0 : (N - 1);
    const int i1 = (s1 < N) ? s1 : (N - 1);

    f32x2 mu2, mub2;
    mu2.x  = mu[i0];      mu2.y  = mu[i1];
    mub2.x = mu_bar[i0];  mub2.y = mu_bar[i1];
    const f32x2 rmu2  = rcp2(mu2 + splat2(EPS));
    const f32x2 rmub2 = rcp2(mub2 + splat2(EPS));

    f32x2 cons2[7];
    cons2[0].x = lw[i0];  cons2[0].y = lw[i1];
    cons2[1].x = h2o[i0]; cons2[1].y = h2o[i1];
    cons2[2].x = o3[i0];  cons2[2].y = o3[i1];
    cons2[3].x = co2[i0]; cons2[3].y = co2[i1];
    cons2[4].x = uu[i0];  cons2[4].y = uu[i1];
    cons2[5].x = n2o[i0]; cons2[5].y = n2o[i1];
    cons2[6].x = ch4[i0]; cons2[6].y = ch4[i1];

    // Hoist ALL tau loads (indexed by absolute chunk) before any store:
    // the chunk loop stays vmem-load-free (R19 finding).
    f32x2 tau2v[4];
#pragma unroll
    for (int k = 0; k < 4; ++k) {
        const int c  = k * 8 + wid;
        const int cc = (c < NCH) ? c : 0;
        tau2v[k].x = tau[(size_t)i0 * NCH + cc];
        tau2v[k].y = tau[(size_t)i1 * NCH + cc];
    }

    int nsamp = N - (int)base;
    if (nsamp > SPB) nsamp = SPB;
    nf4* out4 = (nf4*)out;

    // 4 chunk-phases, rotated per block: chunk k = (k0 + phase) & 3.
#pragma unroll
    for (int k0 = 0; k0 < 4; ++k0) {
        const int k = (k0 + phase) & 3;       // absolute chunk for this block
        const int c = k * 8 + wid;            // wave-uniform channel
        if (c < NCH) {
            const f32x2 td2 = expc2(-(tau2v[k] * rmu2));
            const f32x2 tf2 = expc2(-(tau2v[k] * rmub2));

            f32x2 x2[7];
            f32x2 ed[3], ef[3];
#pragma unroll
            for (int f = 0; f < 7; ++f) x2[f] = cons2[f] * rmu2;
            mlp7p(x2, Wd0 + c * 35, bd0 + c * 5, Wd1 + c * 20, bd1 + c * 4,
                      Wd2 + c * 16, bd2 + c * 4, Wd3 + c * 12, bd3 + c * 3, ed);
#pragma unroll
            for (int f = 0; f < 7; ++f) x2[f] = cons2[f] * rmub2;
            mlp7p(x2, Wf0 + c * 35, bf0 + c * 5, Wf1 + c * 20, bf1 + c * 4,
                      Wf2 + c * 16, bf2 + c * 4, Wf3 + c * 12, bf3 + c * 3, ef);

            const int r = (c - k * 8) * 2;    // local slot 0..15
            obuf[lane * ROWA + r]            = mk4(td2.x, tf2.x, ed[0].x, ed[1].x);
            obuf[lane * ROWA + r + 1]        = mk4(ed[2].x, ef[0].x, ef[1].x, ef[2].x);
            obuf[(lane + 64) * ROWA + r]     = mk4(td2.y, tf2.y, ed[0].y, ed[1].y);
            obuf[(lane + 64) * ROWA + r + 1] = mk4(ed[2].y, ef[0].y, ef[1].y, ef[2].y);
        }

        barrier_lds_only();

        // issue chunk-k stores (fire-and-forget)
        if (nsamp > 0) {
            if (k < 3) {
                const int tot = nsamp * 16;
                for (int i = tid; i < tot; i += 512) {
                    const int s = i >> 4, rr = i & 15;
                    out4[(base + s) * 58 + k * 16 + rr] = obuf[s * ROWA + rr];
                }
            } else {
                const int tot = nsamp * 10;   // 5 channels -> 10 f4 per sample
                for (int i = tid; i < tot; i += 512) {
                    const int s = i / 10, rr = i - s * 10;
                    out4[(base + s) * 58 + 48 + rr] = obuf[s * ROWA + rr];
                }
            }
        }

        barrier_lds_only();   // flush reads done -> obuf reusable
    }
}

extern "C" void kernel_launch(void* const* d_in, const int* in_sizes, int n_in,
                              void* d_out, int out_size, void* d_ws, size_t ws_size,
                              hipStream_t stream) {
    const float* tau    = (const float*)d_in[0];
    const float* mu     = (const float*)d_in[1];
    const float* mu_bar = (const float*)d_in[2];
    const float* lw     = (const float*)d_in[3];
    const float* h2o    = (const float*)d_in[4];
    const float* o3     = (const float*)d_in[5];
    const float* co2    = (const float*)d_in[6];
    const float* uu     = (const float*)d_in[7];
    const float* n2o    = (const float*)d_in[8];
    const float* ch4    = (const float*)d_in[9];

    const float* Wd0 = (const float*)d_in[10];
    const float* bd0 = (const float*)d_in[11];
    const float* Wf0 = (const float*)d_in[12];
    const float* bf0 = (const float*)d_in[13];
    const float* Wd1 = (const float*)d_in[14];
    const float* bd1 = (const float*)d_in[15];
    const float* Wf1 = (const float*)d_in[16];
    const float* bf1 = (const float*)d_in[17];
    const float* Wd2 = (const float*)d_in[18];
    const float* bd2 = (const float*)d_in[19];
    const float* Wf2 = (const float*)d_in[20];
    const float* bf2 = (const float*)d_in[21];
    const float* Wd3 = (const float*)d_in[22];
    const float* bd3 = (const float*)d_in[23];
    const float* Wf3 = (const float*)d_in[24];
    const float* bf3 = (const float*)d_in[25];

    float* out = (float*)d_out;
    int N = in_sizes[1];  // mu has N elements

    int blocks = (N + SPB - 1) / SPB;
    lps_kernel<<<blocks, 512, 0, stream>>>(
        tau, mu, mu_bar, lw, h2o, o3, co2, uu, n2o, ch4,
        Wd0, bd0, Wf0, bf0, Wd1, bd1, Wf1, bf1,
        Wd2, bd2, Wf2, bf2, Wd3, bd3, Wf3, bf3,
        out, N);
}